// Round 9
// baseline (801.923 us; speedup 1.0000x reference)
//
#include <hip/hip_runtime.h>
#include <hip/hip_bf16.h>
#include <hip/hip_cooperative_groups.h>
namespace cg = cooperative_groups;

#define NODES   10000
#define EDGES   320000
#define INF_    256
#define HIDF    128
#define NHEADS  4
#define GRID_B  512
#define NTHR    256
#define GSIZE   (GRID_B * NTHR)        // 131072 threads
#define NWAVES  (GRID_B * (NTHR / 64)) // 2048 waves
#define NSCANB  40                     // ceil(10000/256) scan blocks
#define TILES_M ((NODES + 63) / 64)    // 157

typedef __attribute__((ext_vector_type(8))) short short8v;   // 8 bf16
typedef __attribute__((ext_vector_type(4))) float f32x4;

__device__ __forceinline__ float bf_lo(unsigned z) { return __uint_as_float(z << 16); }
__device__ __forceinline__ float bf_hi(unsigned z) { return __uint_as_float(z & 0xffff0000u); }
__device__ __forceinline__ unsigned short bfr(float x) {
    __hip_bfloat16 b = __float2bfloat16(x);
    return *(unsigned short*)&b;
}

struct P {
    const float* feat; const int* src; const int* dst;
    const float* W1; const float* b1; const float* W2; const float* b2;
    const float* W3; const float* b3; const float* Wg;
    const float* attn_l; const float* attn_r; const float* bg;
    int* deg_o; int* deg_i; int* rowptr; int* cursor; int* csr_src;
    int* btot; int* bpre;
    float* inv_o; float* inv_i; float* WL; float* WR; float* WV; float* cdot;
    float* el; float* er; float* zeta; float* s1v;
    unsigned short* W1t; unsigned short* W2t; unsigned short* Abf;
    unsigned short* Zb; unsigned short* H1b;
    float* out;
};

// ---- MFMA GEMM phase: Y[M,128] = A[M,K] @ Bt[128,K]^T (bf16 in/out, f32 acc) ----
template<int K>
__device__ __forceinline__ void gemm_phase(const unsigned short* __restrict__ A,
                                           const unsigned short* __restrict__ Bt,
                                           unsigned short* __restrict__ Y, int b, int t) {
    for (int vt = b; vt < TILES_M * 2; vt += GRID_B) {
        int w = t >> 6, l = t & 63;
        int m0 = (vt >> 1) * 64 + w * 16;
        int n0 = (vt & 1) * 64;
        int lm = l & 15, lk = (l >> 4) * 8;
        int arow = min(m0 + lm, NODES - 1);
        const short8v* Ap = (const short8v*)(A + (size_t)arow * K + lk);
        const short8v* Bp = (const short8v*)(Bt + (size_t)(n0 + lm) * K + lk);
        f32x4 acc0 = {0.f, 0.f, 0.f, 0.f}, acc1 = acc0, acc2 = acc0, acc3 = acc0;
        const int BS = 2 * K;   // 16 rows * K/8 short8v's
#pragma unroll
        for (int kk = 0; kk < K / 32; ++kk) {
            short8v a = Ap[kk * 4];
            acc0 = __builtin_amdgcn_mfma_f32_16x16x32_bf16(a, Bp[kk * 4], acc0, 0, 0, 0);
            acc1 = __builtin_amdgcn_mfma_f32_16x16x32_bf16(a, Bp[kk * 4 + BS], acc1, 0, 0, 0);
            acc2 = __builtin_amdgcn_mfma_f32_16x16x32_bf16(a, Bp[kk * 4 + 2 * BS], acc2, 0, 0, 0);
            acc3 = __builtin_amdgcn_mfma_f32_16x16x32_bf16(a, Bp[kk * 4 + 3 * BS], acc3, 0, 0, 0);
        }
        int rb = m0 + (l >> 4) * 4;
        int cb = n0 + lm;
        f32x4 accs[4] = {acc0, acc1, acc2, acc3};
#pragma unroll
        for (int j = 0; j < 4; ++j) {
            int c = cb + 16 * j;
#pragma unroll
            for (int r = 0; r < 4; ++r) {
                int row = rb + r;
                if (row < NODES) Y[(size_t)row * HIDF + c] = bfr(accs[j][r]);
            }
        }
    }
}

// ---- gather core: v[8] = relu(inv_i[n]*sum_{s in N(n)} inv_o[s]*Z[s, 8q..8q+7] + b) ----
__device__ __forceinline__ void gather_core(int n, int l, const int* __restrict__ rowptr,
                                            const int* __restrict__ csr,
                                            const unsigned short* __restrict__ Zb,
                                            const float* __restrict__ inv_o,
                                            const float* __restrict__ inv_i,
                                            const float* __restrict__ bias, float v[8]) {
    int quarter = l >> 4, q = l & 15;
    int beg = rowptr[n], end = rowptr[n + 1];
    float a[8] = {0.f, 0.f, 0.f, 0.f, 0.f, 0.f, 0.f, 0.f};
    for (int i = beg + quarter; i < end; i += 4) {
        int s = csr[i];
        float so = inv_o[s];
        uint4 z = *(const uint4*)&Zb[s * HIDF + 8 * q];
        a[0] = fmaf(so, bf_lo(z.x), a[0]); a[1] = fmaf(so, bf_hi(z.x), a[1]);
        a[2] = fmaf(so, bf_lo(z.y), a[2]); a[3] = fmaf(so, bf_hi(z.y), a[3]);
        a[4] = fmaf(so, bf_lo(z.z), a[4]); a[5] = fmaf(so, bf_hi(z.z), a[5]);
        a[6] = fmaf(so, bf_lo(z.w), a[6]); a[7] = fmaf(so, bf_hi(z.w), a[7]);
    }
#pragma unroll
    for (int j = 0; j < 8; ++j) {
        a[j] += __shfl_xor(a[j], 16, 64);
        a[j] += __shfl_xor(a[j], 32, 64);
    }
    float sc = inv_i[n];
#pragma unroll
    for (int j = 0; j < 8; ++j) v[j] = fmaxf(fmaf(a[j], sc, bias[8 * q + j]), 0.f);
}

__global__ __launch_bounds__(NTHR, 2)
void mega(P p) {
    cg::grid_group grid = cg::this_grid();
    const int b = blockIdx.x, t = threadIdx.x;
    const int gtid = b * NTHR + t;
    __shared__ int s_scan[NTHR];

    // ===== Phase 0: weight prep + attn fold + cdot + zero degrees + feat->bf16 =====
    for (int id = gtid; id < 128 * 256; id += GSIZE) {       // W1 [256][128] -> W1t [128][256]
        int nn = id >> 8, k = id & 255;
        p.W1t[id] = bfr(p.W1[k * HIDF + nn]);
    }
    for (int id = gtid; id < 128 * 128; id += GSIZE) {       // W2 -> W2t [128][128]
        int nn = id >> 7, k = id & 127;
        p.W2t[id] = bfr(p.W2[k * HIDF + nn]);
    }
    if (gtid < 512) {                                        // WL/WR/WV folds
        int k = gtid >> 2, h = gtid & 3;
        float a = 0.f, bb = 0.f, c = 0.f;
        for (int d = 0; d < HIDF; ++d) {
            float w_ = p.Wg[k * 512 + h * HIDF + d];
            a = fmaf(w_, p.attn_l[h * HIDF + d], a);
            bb = fmaf(w_, p.attn_r[h * HIDF + d], bb);
            c = fmaf(w_, p.W3[d], c);
        }
        p.WL[gtid] = a; p.WR[gtid] = bb; p.WV[gtid] = c;
    }
    if (b == 0 && t < 64) {                                  // cdot = 0.25*(sum_h bg_h).W3
        float s = 0.f;
        for (int d = t; d < HIDF; d += 64)
            s += (p.bg[d] + p.bg[d + 128] + p.bg[d + 256] + p.bg[d + 384]) * p.W3[d];
#pragma unroll
        for (int off = 32; off; off >>= 1) s += __shfl_xor(s, off, 64);
        if (t == 0) p.cdot[0] = 0.25f * s;
    }
    for (int id = gtid; id < 2 * NODES; id += GSIZE) p.deg_o[id] = 0;  // deg_o|deg_i contig
    for (int id = gtid; id < NODES * (INF_ / 4); id += GSIZE) {        // feat -> bf16 (unscaled)
        float4 v = ((const float4*)p.feat)[id];
        uint2 o;
        o.x = ((unsigned)bfr(v.y) << 16) | bfr(v.x);
        o.y = ((unsigned)bfr(v.w) << 16) | bfr(v.z);
        ((uint2*)p.Abf)[id] = o;
    }
    grid.sync();

    // ===== Phase A: degree atomics =====
    for (int e = gtid; e < EDGES; e += GSIZE) {
        atomicAdd(&p.deg_o[p.src[e]], 1);
        atomicAdd(&p.deg_i[p.dst[e]], 1);
    }
    grid.sync();

    // ===== Phase B1: per-block inclusive scan of deg_i chunks =====
    int myv = 0;
    if (b < NSCANB) {
        int node = b * NTHR + t;
        myv = (node < NODES) ? p.deg_i[node] : 0;
        s_scan[t] = myv;
        __syncthreads();
        for (int off = 1; off < NTHR; off <<= 1) {
            int x = (t >= off) ? s_scan[t - off] : 0;
            __syncthreads();
            s_scan[t] += x;
            __syncthreads();
        }
        if (t == NTHR - 1) p.btot[b] = s_scan[t];
    }
    grid.sync();
    // ===== Phase B2: scan of 40 block totals (one wave) =====
    if (b == 0 && t < 64) {
        int v = (t < NSCANB) ? p.btot[t] : 0;
        int incl = v;
#pragma unroll
        for (int off = 1; off < 64; off <<= 1) {
            int x = __shfl_up(incl, off, 64);
            if (t >= off) incl += x;
        }
        if (t < NSCANB) p.bpre[t] = incl - v;
        if (t == NSCANB - 1) p.rowptr[NODES] = incl;
    }
    grid.sync();
    // ===== Phase B3: finalize rowptr/cursor/inv (LDS persists across grid.sync) =====
    if (b < NSCANB) {
        int node = b * NTHR + t;
        if (node < NODES) {
            int base = p.bpre[b] + s_scan[t] - myv;   // exclusive prefix
            p.rowptr[node] = base;
            p.cursor[node] = base;
            p.inv_i[node] = rsqrtf(fmaxf((float)myv, 1.0f));
            p.inv_o[node] = rsqrtf(fmaxf((float)p.deg_o[node], 1.0f));
        }
    }
    grid.sync();

    // ===== Phase C: csr fill =====
    for (int e = gtid; e < EDGES; e += GSIZE) {
        int pos = atomicAdd(&p.cursor[p.dst[e]], 1);
        p.csr_src[pos] = p.src[e];
    }
    grid.sync();

    // ===== Phase D: GEMM1  Zb = Abf @ W1t^T =====
    gemm_phase<INF_>(p.Abf, p.W1t, p.Zb, b, t);
    grid.sync();

    // ===== Phase E: gather1 -> H1b (relu, unscaled bf16) =====
    {
        int gw = gtid >> 6, l = t & 63, q = l & 15;
        for (int n = gw; n < NODES; n += NWAVES) {
            float v[8];
            gather_core(n, l, p.rowptr, p.csr_src, p.Zb, p.inv_o, p.inv_i, p.b1, v);
            if (l < 16) {
                uint4 o;
                o.x = ((unsigned)bfr(v[1]) << 16) | bfr(v[0]);
                o.y = ((unsigned)bfr(v[3]) << 16) | bfr(v[2]);
                o.z = ((unsigned)bfr(v[5]) << 16) | bfr(v[4]);
                o.w = ((unsigned)bfr(v[7]) << 16) | bfr(v[6]);
                *(uint4*)&p.H1b[n * HIDF + 8 * q] = o;
            }
        }
    }
    grid.sync();

    // ===== Phase F: GEMM2  Zb = H1b @ W2t^T =====
    gemm_phase<HIDF>(p.H1b, p.W2t, p.Zb, b, t);
    grid.sync();

    // ===== Phase G: gather2 -> el/er/zeta (H2 never materialized) =====
    {
        int gw = gtid >> 6, l = t & 63, q = l & 15;
        for (int n = gw; n < NODES; n += NWAVES) {
            float v[8];
            gather_core(n, l, p.rowptr, p.csr_src, p.Zb, p.inv_o, p.inv_i, p.b2, v);
            float elh[NHEADS] = {0.f, 0.f, 0.f, 0.f};
            float erh[NHEADS] = {0.f, 0.f, 0.f, 0.f};
            float zth[NHEADS] = {0.f, 0.f, 0.f, 0.f};
#pragma unroll
            for (int j = 0; j < 8; ++j) {
                int k = 8 * q + j;
#pragma unroll
                for (int h = 0; h < NHEADS; ++h) {
                    elh[h] = fmaf(v[j], p.WL[k * NHEADS + h], elh[h]);
                    erh[h] = fmaf(v[j], p.WR[k * NHEADS + h], erh[h]);
                    zth[h] = fmaf(v[j], p.WV[k * NHEADS + h], zth[h]);
                }
            }
#pragma unroll
            for (int h = 0; h < NHEADS; ++h) {
#pragma unroll
                for (int off = 1; off <= 8; off <<= 1) {
                    elh[h] += __shfl_xor(elh[h], off, 64);
                    erh[h] += __shfl_xor(erh[h], off, 64);
                    zth[h] += __shfl_xor(zth[h], off, 64);
                }
            }
            if (l == 0) {
#pragma unroll
                for (int h = 0; h < NHEADS; ++h) {
                    p.el[n * NHEADS + h] = elh[h];
                    p.er[n * NHEADS + h] = erh[h];
                    p.zeta[n * NHEADS + h] = zth[h];
                }
            }
        }
    }
    grid.sync();

    // ===== Phase H: GAT collapsed -> s1v =====
    {
        const float4* el4 = (const float4*)p.el;
        const float4* er4 = (const float4*)p.er;
        const float4* zeta4 = (const float4*)p.zeta;
        int gw = gtid >> 6, l = t & 63;
        for (int n = gw; n < NODES; n += NWAVES) {
            int beg = p.rowptr[n], end = p.rowptr[n + 1];
            float4 ern = er4[n];
            int i0 = beg + l, i1 = beg + 64 + l;
            float lg0[4] = {-1e30f, -1e30f, -1e30f, -1e30f};
            float lg1[4] = {-1e30f, -1e30f, -1e30f, -1e30f};
            float zt0[4] = {0.f, 0.f, 0.f, 0.f}, zt1[4] = {0.f, 0.f, 0.f, 0.f};
            if (i0 < end) {
                int s = p.csr_src[i0];
                float4 e = el4[s], z = zeta4[s];
                float tt;
                tt = e.x + ern.x; lg0[0] = tt > 0.f ? tt : 0.2f * tt; zt0[0] = z.x;
                tt = e.y + ern.y; lg0[1] = tt > 0.f ? tt : 0.2f * tt; zt0[1] = z.y;
                tt = e.z + ern.z; lg0[2] = tt > 0.f ? tt : 0.2f * tt; zt0[2] = z.z;
                tt = e.w + ern.w; lg0[3] = tt > 0.f ? tt : 0.2f * tt; zt0[3] = z.w;
            }
            if (i1 < end) {
                int s = p.csr_src[i1];
                float4 e = el4[s], z = zeta4[s];
                float tt;
                tt = e.x + ern.x; lg1[0] = tt > 0.f ? tt : 0.2f * tt; zt1[0] = z.x;
                tt = e.y + ern.y; lg1[1] = tt > 0.f ? tt : 0.2f * tt; zt1[1] = z.y;
                tt = e.z + ern.z; lg1[2] = tt > 0.f ? tt : 0.2f * tt; zt1[2] = z.z;
                tt = e.w + ern.w; lg1[3] = tt > 0.f ? tt : 0.2f * tt; zt1[3] = z.w;
            }
            float m[4], den[4], acc[4];
#pragma unroll
            for (int h = 0; h < 4; ++h) m[h] = fmaxf(lg0[h], lg1[h]);
#pragma unroll
            for (int off = 32; off; off >>= 1)
#pragma unroll
                for (int h = 0; h < 4; ++h) m[h] = fmaxf(m[h], __shfl_xor(m[h], off, 64));
#pragma unroll
            for (int h = 0; h < 4; ++h) {
                float e0 = (i0 < end) ? __expf(lg0[h] - m[h]) : 0.f;
                float e1 = (i1 < end) ? __expf(lg1[h] - m[h]) : 0.f;
                den[h] = e0 + e1;
                acc[h] = e0 * zt0[h] + e1 * zt1[h];
            }
#pragma unroll
            for (int off = 32; off; off >>= 1)
#pragma unroll
                for (int h = 0; h < 4; ++h) {
                    den[h] += __shfl_xor(den[h], off, 64);
                    acc[h] += __shfl_xor(acc[h], off, 64);
                }
            if (l == 0) {
                float s = 0.f;
#pragma unroll
                for (int h = 0; h < 4; ++h) s += den[h] > 0.f ? acc[h] / den[h] : 0.f;
                p.s1v[n] = p.inv_o[n] * (0.25f * s + p.cdot[0]);
            }
        }
    }
    grid.sync();

    // ===== Phase I: GC3 gather + sigmoid -> out =====
    {
        int gw = gtid >> 6, l = t & 63;
        for (int n = gw; n < NODES; n += NWAVES) {
            int beg = p.rowptr[n], end = p.rowptr[n + 1];
            float acc = 0.f;
            for (int i = beg + l; i < end; i += 64) acc += p.s1v[p.csr_src[i]];
#pragma unroll
            for (int off = 32; off; off >>= 1) acc += __shfl_xor(acc, off, 64);
            if (l == 0) {
                float xv = acc * p.inv_i[n] + p.b3[0];
                p.out[n] = 1.f / (1.f + __expf(-xv));
            }
        }
    }
}

extern "C" void kernel_launch(void* const* d_in, const int* in_sizes, int n_in,
                              void* d_out, int out_size, void* d_ws, size_t ws_size,
                              hipStream_t stream) {
    char* w = (char*)d_ws;
    auto alloc = [&](size_t bytes) { void* q = (void*)w; w += (bytes + 255) & ~(size_t)255; return q; };

    P p;
    p.feat   = (const float*)d_in[0];
    p.src    = (const int*)d_in[1];
    p.dst    = (const int*)d_in[2];
    p.W1     = (const float*)d_in[3];
    p.b1     = (const float*)d_in[4];
    p.W2     = (const float*)d_in[5];
    p.b2     = (const float*)d_in[6];
    p.W3     = (const float*)d_in[7];
    p.b3     = (const float*)d_in[8];
    p.Wg     = (const float*)d_in[9];
    p.attn_l = (const float*)d_in[10];
    p.attn_r = (const float*)d_in[11];
    p.bg     = (const float*)d_in[12];

    p.deg_o   = (int*)alloc(2 * NODES * 4);       // deg_o | deg_i contiguous
    p.deg_i   = p.deg_o + NODES;
    p.rowptr  = (int*)alloc((NODES + 1) * 4);
    p.cursor  = (int*)alloc(NODES * 4);
    p.csr_src = (int*)alloc((size_t)EDGES * 4);
    p.btot    = (int*)alloc(64 * 4);
    p.bpre    = (int*)alloc(64 * 4);
    p.inv_o   = (float*)alloc(NODES * 4);
    p.inv_i   = (float*)alloc(NODES * 4);
    p.WL      = (float*)alloc(HIDF * NHEADS * 4);
    p.WR      = (float*)alloc(HIDF * NHEADS * 4);
    p.WV      = (float*)alloc(HIDF * NHEADS * 4);
    p.cdot    = (float*)alloc(256);
    p.el      = (float*)alloc(NODES * NHEADS * 4);
    p.er      = (float*)alloc(NODES * NHEADS * 4);
    p.zeta    = (float*)alloc(NODES * NHEADS * 4);
    p.s1v     = (float*)alloc(NODES * 4);
    p.W1t     = (unsigned short*)alloc(128 * 256 * 2);
    p.W2t     = (unsigned short*)alloc(128 * 128 * 2);
    p.Abf     = (unsigned short*)alloc((size_t)NODES * INF_ * 2);
    p.Zb      = (unsigned short*)alloc((size_t)NODES * HIDF * 2);
    p.H1b     = (unsigned short*)alloc((size_t)NODES * HIDF * 2);
    p.out     = (float*)d_out;

    void* args[] = {(void*)&p};
    hipLaunchCooperativeKernel((const void*)mega, dim3(GRID_B), dim3(NTHR), args, 0, stream);
}

// Round 10
// 190.159 us; speedup vs baseline: 4.2171x; 4.2171x over previous
//
#include <hip/hip_runtime.h>
#include <hip/hip_bf16.h>

#define NODES   10000
#define EDGES   320000
#define INF_    256
#define HIDF    128
#define NHEADS  4
#define SCAN_T  1024
#define SCAN_C  10
#define EDGE_BLKS   ((EDGES + 255) / 256)           // 1250
#define FEAT_ITEMS  (NODES * (INF_ / 8))            // 320000 uint2 items (8 bf16 each... 4 floats)
#define W_BLKS      96                              // (128*256 + 128*128) / 512
#define FOLD_BLK    W_BLKS                          // 1 block
#define ZERO_BLKS   40                              // 2*NODES / 512
#define FEAT_BLKS   ((NODES * (INF_ / 4) + 511) / 512)   // 1250 (uint2 per 4 floats)
#define PREP_BLKS   (W_BLKS + 1 + ZERO_BLKS + FEAT_BLKS)

typedef __attribute__((ext_vector_type(8))) short short8v;   // 8 bf16
typedef __attribute__((ext_vector_type(4))) float f32x4;

__device__ __forceinline__ float bf_lo(unsigned z) { return __uint_as_float(z << 16); }
__device__ __forceinline__ float bf_hi(unsigned z) { return __uint_as_float(z & 0xffff0000u); }
__device__ __forceinline__ unsigned short bfr(float x) {
    __hip_bfloat16 b = __float2bfloat16(x);
    return *(unsigned short*)&b;
}

// ---------------- degree ----------------
__global__ void deg_kernel(const int* __restrict__ src, const int* __restrict__ dst,
                           int* __restrict__ deg_o, int* __restrict__ deg_i) {
    int e = blockIdx.x * blockDim.x + threadIdx.x;
    if (e < EDGES) {
        atomicAdd(&deg_o[src[e]], 1);
        atomicAdd(&deg_i[dst[e]], 1);
    }
}

// ---------------- scan of deg_i -> rowptr/cursor, plus inv norms ----------------
__global__ void scan_inv(const int* __restrict__ deg_i, const int* __restrict__ deg_o,
                         int* __restrict__ rowptr, int* __restrict__ cursor,
                         float* __restrict__ inv_o, float* __restrict__ inv_i) {
    __shared__ int part[SCAN_T];
    int t = threadIdx.x;
    int base = t * SCAN_C;
    int local[SCAN_C];
    int s = 0;
    for (int j = 0; j < SCAN_C; ++j) {
        int idx = base + j;
        int v = idx < NODES ? deg_i[idx] : 0;
        local[j] = s;
        s += v;
    }
    part[t] = s;
    __syncthreads();
    for (int off = 1; off < SCAN_T; off <<= 1) {
        int v = (t >= off) ? part[t - off] : 0;
        __syncthreads();
        part[t] += v;
        __syncthreads();
    }
    int offs = (t > 0) ? part[t - 1] : 0;
    for (int j = 0; j < SCAN_C; ++j) {
        int idx = base + j;
        if (idx < NODES) {
            int r = offs + local[j];
            rowptr[idx] = r;
            cursor[idx] = r;
            inv_i[idx] = rsqrtf(fmaxf((float)deg_i[idx], 1.0f));
            inv_o[idx] = rsqrtf(fmaxf((float)deg_o[idx], 1.0f));
        }
    }
    if (t == SCAN_T - 1) rowptr[NODES] = part[SCAN_T - 1];
}

// ---- prep0: weights->bf16^T, attn/W3 folds, cdot, zero degrees, feat->bf16 (unscaled) ----
__global__ __launch_bounds__(512)
void prep0(const float* __restrict__ W1, const float* __restrict__ W2,
           const float* __restrict__ Wg, const float* __restrict__ attn_l,
           const float* __restrict__ attn_r, const float* __restrict__ bg,
           const float* __restrict__ W3, const float* __restrict__ feat,
           unsigned short* __restrict__ W1t, unsigned short* __restrict__ W2t,
           float* __restrict__ WL, float* __restrict__ WR, float* __restrict__ WV,
           float* __restrict__ cdot, int* __restrict__ deg,
           unsigned short* __restrict__ Abf) {
    int b = blockIdx.x;
    if (b < W_BLKS) {
        int id = b * 512 + threadIdx.x;
        if (id < 128 * 256) {                 // W1 [256][128] -> W1t [128][256]
            int nn = id >> 8, k = id & 255;
            W1t[id] = bfr(W1[k * HIDF + nn]);
        } else {                              // W2 [128][128] -> W2t [128][128]
            id -= 128 * 256;
            int nn = id >> 7, k = id & 127;
            W2t[id] = bfr(W2[k * HIDF + nn]);
        }
        return;
    }
    if (b == FOLD_BLK) {                      // WL/WR/WV folds + cdot
        __shared__ float red[HIDF];
        int id = threadIdx.x;  // 512
        int k = id >> 2, h = id & 3;
        float a = 0.f, bb = 0.f, c = 0.f;
        for (int d = 0; d < HIDF; ++d) {
            float w = Wg[k * 512 + h * HIDF + d];
            a = fmaf(w, attn_l[h * HIDF + d], a);
            bb = fmaf(w, attn_r[h * HIDF + d], bb);
            c = fmaf(w, W3[d], c);
        }
        WL[id] = a; WR[id] = bb; WV[id] = c;
        if (id < HIDF) red[id] = (bg[id] + bg[id + 128] + bg[id + 256] + bg[id + 384]) * W3[id];
        __syncthreads();
        if (id == 0) {
            float s = 0.f;
            for (int t = 0; t < HIDF; ++t) s += red[t];
            cdot[0] = 0.25f * s;
        }
        return;
    }
    if (b <= FOLD_BLK + ZERO_BLKS) {          // zero deg_o|deg_i (2*NODES ints)
        int id = (b - FOLD_BLK - 1) * 512 + threadIdx.x;
        if (id < 2 * NODES) deg[id] = 0;
        return;
    }
    // feat -> bf16, unscaled
    int id = (b - FOLD_BLK - 1 - ZERO_BLKS) * 512 + threadIdx.x;
    if (id < NODES * (INF_ / 4)) {
        float4 v = ((const float4*)feat)[id];
        uint2 o;
        o.x = ((unsigned)bfr(v.y) << 16) | bfr(v.x);
        o.y = ((unsigned)bfr(v.w) << 16) | bfr(v.z);
        ((uint2*)Abf)[id] = o;
    }
}

// ---------------- csr fill ----------------
__global__ void csr_fill(const int* __restrict__ src, const int* __restrict__ dst,
                         int* __restrict__ cursor, int* __restrict__ csr_src) {
    int e = blockIdx.x * blockDim.x + threadIdx.x;
    if (e < EDGES) {
        int pos = atomicAdd(&cursor[dst[e]], 1);
        csr_src[pos] = src[e];
    }
}

// ---- MFMA GEMM: Y[row] = inv_o[row] * (A[M,K] @ Bt[128,K]^T)[row], bf16 out ----
template<int K>
__global__ __launch_bounds__(256)
void mfma_gemm(const unsigned short* __restrict__ A, const unsigned short* __restrict__ Bt,
               const float* __restrict__ inv_o, unsigned short* __restrict__ Y) {
    int w = threadIdx.x >> 6, l = threadIdx.x & 63;
    int m0 = blockIdx.x * 64 + w * 16;
    int n0 = blockIdx.y * 64;
    int lm = l & 15, lk = (l >> 4) * 8;
    int arow = min(m0 + lm, NODES - 1);
    const short8v* Ap = (const short8v*)(A + (size_t)arow * K + lk);
    const short8v* Bp = (const short8v*)(Bt + (size_t)(n0 + lm) * K + lk);
    f32x4 acc0 = {0.f, 0.f, 0.f, 0.f}, acc1 = acc0, acc2 = acc0, acc3 = acc0;
    const int BS = 2 * K;   // 16 rows * K/8 short8v's
#pragma unroll
    for (int kk = 0; kk < K / 32; ++kk) {
        short8v a = Ap[kk * 4];
        acc0 = __builtin_amdgcn_mfma_f32_16x16x32_bf16(a, Bp[kk * 4], acc0, 0, 0, 0);
        acc1 = __builtin_amdgcn_mfma_f32_16x16x32_bf16(a, Bp[kk * 4 + BS], acc1, 0, 0, 0);
        acc2 = __builtin_amdgcn_mfma_f32_16x16x32_bf16(a, Bp[kk * 4 + 2 * BS], acc2, 0, 0, 0);
        acc3 = __builtin_amdgcn_mfma_f32_16x16x32_bf16(a, Bp[kk * 4 + 3 * BS], acc3, 0, 0, 0);
    }
    int rb = m0 + (l >> 4) * 4;
    int cb = n0 + lm;
    f32x4 accs[4] = {acc0, acc1, acc2, acc3};
#pragma unroll
    for (int r = 0; r < 4; ++r) {
        int row = rb + r;
        if (row < NODES) {
            float so = inv_o[row];
#pragma unroll
            for (int j = 0; j < 4; ++j) {
                Y[(size_t)row * HIDF + cb + 16 * j] = bfr(accs[j][r] * so);
            }
        }
    }
}

// ---- gather core: a[8] = sum_{s in N(n)} Zb[s, 8q..8q+7]  (Zb pre-scaled by inv_o) ----
// 8 rows in flight: quarters stride 4, each iteration loads 2 independent (csr,row) pairs.
__device__ __forceinline__ void gather_core(int n, int l, const int* __restrict__ rowptr,
                                            const int* __restrict__ csr,
                                            const unsigned short* __restrict__ Zb,
                                            float a[8], int& beg, int& end) {
    int quarter = l >> 4, q = l & 15;
    beg = rowptr[n]; end = rowptr[n + 1];
#pragma unroll
    for (int j = 0; j < 8; ++j) a[j] = 0.f;
    int i = beg + quarter;
    for (; i + 4 < end; i += 8) {
        int s0 = csr[i];
        int s1 = csr[i + 4];
        uint4 z0 = *(const uint4*)&Zb[s0 * HIDF + 8 * q];
        uint4 z1 = *(const uint4*)&Zb[s1 * HIDF + 8 * q];
        a[0] += bf_lo(z0.x); a[1] += bf_hi(z0.x);
        a[2] += bf_lo(z0.y); a[3] += bf_hi(z0.y);
        a[4] += bf_lo(z0.z); a[5] += bf_hi(z0.z);
        a[6] += bf_lo(z0.w); a[7] += bf_hi(z0.w);
        a[0] += bf_lo(z1.x); a[1] += bf_hi(z1.x);
        a[2] += bf_lo(z1.y); a[3] += bf_hi(z1.y);
        a[4] += bf_lo(z1.z); a[5] += bf_hi(z1.z);
        a[6] += bf_lo(z1.w); a[7] += bf_hi(z1.w);
    }
    if (i < end) {
        int s0 = csr[i];
        uint4 z0 = *(const uint4*)&Zb[s0 * HIDF + 8 * q];
        a[0] += bf_lo(z0.x); a[1] += bf_hi(z0.x);
        a[2] += bf_lo(z0.y); a[3] += bf_hi(z0.y);
        a[4] += bf_lo(z0.z); a[5] += bf_hi(z0.z);
        a[6] += bf_lo(z0.w); a[7] += bf_hi(z0.w);
    }
#pragma unroll
    for (int j = 0; j < 8; ++j) {
        a[j] += __shfl_xor(a[j], 16, 64);
        a[j] += __shfl_xor(a[j], 32, 64);
    }
}

// MODE 1: Hb = bf16(relu(agg*inv_i + b))      (feeds GEMM2; inv_o applied there)
// MODE 2: el/er/zeta from v via WL/WR/WV
template<int MODE>
__global__ __launch_bounds__(64)
void gc_gather(const int* __restrict__ rowptr, const int* __restrict__ csr_src,
               const unsigned short* __restrict__ Zb, const float* __restrict__ inv_i,
               const float* __restrict__ bias, unsigned short* __restrict__ Hb,
               const float* __restrict__ WL, const float* __restrict__ WR,
               const float* __restrict__ WV, float* __restrict__ el,
               float* __restrict__ er, float* __restrict__ zeta) {
    int n = blockIdx.x;
    int l = threadIdx.x;
    int q = l & 15;
    float a[8];
    int beg, end;
    gather_core(n, l, rowptr, csr_src, Zb, a, beg, end);
    float sc = inv_i[n];
    float v[8];
#pragma unroll
    for (int j = 0; j < 8; ++j) v[j] = fmaxf(fmaf(a[j], sc, bias[8 * q + j]), 0.f);
    if (MODE == 1) {
        if (l < 16) {
            uint4 o;
            o.x = ((unsigned)bfr(v[1]) << 16) | bfr(v[0]);
            o.y = ((unsigned)bfr(v[3]) << 16) | bfr(v[2]);
            o.z = ((unsigned)bfr(v[5]) << 16) | bfr(v[4]);
            o.w = ((unsigned)bfr(v[7]) << 16) | bfr(v[6]);
            *(uint4*)&Hb[n * HIDF + 8 * q] = o;
        }
    }
    if (MODE == 2) {
        float elh[NHEADS] = {0.f, 0.f, 0.f, 0.f};
        float erh[NHEADS] = {0.f, 0.f, 0.f, 0.f};
        float zth[NHEADS] = {0.f, 0.f, 0.f, 0.f};
#pragma unroll
        for (int j = 0; j < 8; ++j) {
            int k = 8 * q + j;
#pragma unroll
            for (int h = 0; h < NHEADS; ++h) {
                elh[h] = fmaf(v[j], WL[k * NHEADS + h], elh[h]);
                erh[h] = fmaf(v[j], WR[k * NHEADS + h], erh[h]);
                zth[h] = fmaf(v[j], WV[k * NHEADS + h], zth[h]);
            }
        }
#pragma unroll
        for (int h = 0; h < NHEADS; ++h) {
#pragma unroll
            for (int off = 1; off <= 8; off <<= 1) {
                elh[h] += __shfl_xor(elh[h], off, 64);
                erh[h] += __shfl_xor(erh[h], off, 64);
                zth[h] += __shfl_xor(zth[h], off, 64);
            }
        }
        if (l == 0) {
#pragma unroll
            for (int h = 0; h < NHEADS; ++h) {
                el[n * NHEADS + h] = elh[h];
                er[n * NHEADS + h] = erh[h];
                zeta[n * NHEADS + h] = zth[h];
            }
        }
    }
}

// ---- GAT collapsed: 1 wave/node, 4 heads as float4, scalar zeta aggregation ----
__global__ __launch_bounds__(64)
void gat_s1(const int* __restrict__ rowptr, const int* __restrict__ csr_src,
            const float4* __restrict__ el4, const float4* __restrict__ er4,
            const float4* __restrict__ zeta4, const float* __restrict__ inv_o,
            const float* __restrict__ cdot, float* __restrict__ s1v) {
    int n = blockIdx.x;
    int l = threadIdx.x;
    int beg = rowptr[n], end = rowptr[n + 1];
    float4 ern = er4[n];
    int i0 = beg + l, i1 = beg + 64 + l;
    float lg0[4] = {-1e30f, -1e30f, -1e30f, -1e30f};
    float lg1[4] = {-1e30f, -1e30f, -1e30f, -1e30f};
    float zt0[4] = {0.f, 0.f, 0.f, 0.f}, zt1[4] = {0.f, 0.f, 0.f, 0.f};
    if (i0 < end) {
        int s = csr_src[i0];
        float4 e = el4[s], z = zeta4[s];
        float t;
        t = e.x + ern.x; lg0[0] = t > 0.f ? t : 0.2f * t; zt0[0] = z.x;
        t = e.y + ern.y; lg0[1] = t > 0.f ? t : 0.2f * t; zt0[1] = z.y;
        t = e.z + ern.z; lg0[2] = t > 0.f ? t : 0.2f * t; zt0[2] = z.z;
        t = e.w + ern.w; lg0[3] = t > 0.f ? t : 0.2f * t; zt0[3] = z.w;
    }
    if (i1 < end) {
        int s = csr_src[i1];
        float4 e = el4[s], z = zeta4[s];
        float t;
        t = e.x + ern.x; lg1[0] = t > 0.f ? t : 0.2f * t; zt1[0] = z.x;
        t = e.y + ern.y; lg1[1] = t > 0.f ? t : 0.2f * t; zt1[1] = z.y;
        t = e.z + ern.z; lg1[2] = t > 0.f ? t : 0.2f * t; zt1[2] = z.z;
        t = e.w + ern.w; lg1[3] = t > 0.f ? t : 0.2f * t; zt1[3] = z.w;
    }
    float m[4], den[4], acc[4];
#pragma unroll
    for (int h = 0; h < 4; ++h) m[h] = fmaxf(lg0[h], lg1[h]);
#pragma unroll
    for (int off = 32; off; off >>= 1)
#pragma unroll
        for (int h = 0; h < 4; ++h) m[h] = fmaxf(m[h], __shfl_xor(m[h], off, 64));
#pragma unroll
    for (int h = 0; h < 4; ++h) {
        float e0 = (i0 < end) ? __expf(lg0[h] - m[h]) : 0.f;
        float e1 = (i1 < end) ? __expf(lg1[h] - m[h]) : 0.f;
        den[h] = e0 + e1;
        acc[h] = e0 * zt0[h] + e1 * zt1[h];
    }
#pragma unroll
    for (int off = 32; off; off >>= 1)
#pragma unroll
        for (int h = 0; h < 4; ++h) {
            den[h] += __shfl_xor(den[h], off, 64);
            acc[h] += __shfl_xor(acc[h], off, 64);
        }
    if (l == 0) {
        float s = 0.f;
#pragma unroll
        for (int h = 0; h < 4; ++h) s += den[h] > 0.f ? acc[h] / den[h] : 0.f;
        s1v[n] = inv_o[n] * (0.25f * s + cdot[0]);
    }
}

// ---------------- GC3 gather + sigmoid: 1 wave/node ----------------
__global__ __launch_bounds__(64)
void gc3_gather(const int* __restrict__ rowptr, const int* __restrict__ csr_src,
                const float* __restrict__ s1v, const float* __restrict__ inv_i,
                const float* __restrict__ b3, float* __restrict__ out) {
    int n = blockIdx.x;
    int l = threadIdx.x;
    int beg = rowptr[n], end = rowptr[n + 1];
    float acc = 0.f;
    for (int i = beg + l; i < end; i += 64) acc += s1v[csr_src[i]];
#pragma unroll
    for (int off = 32; off; off >>= 1) acc += __shfl_xor(acc, off, 64);
    if (l == 0) {
        float xv = acc * inv_i[n] + b3[0];
        out[n] = 1.f / (1.f + __expf(-xv));
    }
}

extern "C" void kernel_launch(void* const* d_in, const int* in_sizes, int n_in,
                              void* d_out, int out_size, void* d_ws, size_t ws_size,
                              hipStream_t stream) {
    const float* feat   = (const float*)d_in[0];
    const int*   src    = (const int*)d_in[1];
    const int*   dst    = (const int*)d_in[2];
    const float* W1     = (const float*)d_in[3];
    const float* b1     = (const float*)d_in[4];
    const float* W2     = (const float*)d_in[5];
    const float* b2     = (const float*)d_in[6];
    const float* W3     = (const float*)d_in[7];
    const float* b3     = (const float*)d_in[8];
    const float* Wg     = (const float*)d_in[9];
    const float* attn_l = (const float*)d_in[10];
    const float* attn_r = (const float*)d_in[11];
    const float* bg     = (const float*)d_in[12];

    char* w = (char*)d_ws;
    auto alloc = [&](size_t bytes) { void* p = (void*)w; w += (bytes + 255) & ~(size_t)255; return p; };
    int*   deg     = (int*)  alloc(2 * NODES * 4);   // deg_o | deg_i contiguous
    int*   deg_o   = deg;
    int*   deg_i   = deg + NODES;
    float* inv_o   = (float*)alloc(NODES * 4);
    float* inv_i   = (float*)alloc(NODES * 4);
    int*   rowptr  = (int*)  alloc((NODES + 1) * 4);
    int*   cursor  = (int*)  alloc(NODES * 4);
    int*   csr_src = (int*)  alloc((size_t)EDGES * 4);
    unsigned short* W1t = (unsigned short*)alloc(128 * 256 * 2);
    unsigned short* W2t = (unsigned short*)alloc(128 * 128 * 2);
    float* WL      = (float*)alloc(HIDF * NHEADS * 4);
    float* WR      = (float*)alloc(HIDF * NHEADS * 4);
    float* WV      = (float*)alloc(HIDF * NHEADS * 4);
    float* cdot    = (float*)alloc(256);
    float* el      = (float*)alloc(NODES * NHEADS * 4);
    float* er      = (float*)alloc(NODES * NHEADS * 4);
    float* zeta    = (float*)alloc(NODES * NHEADS * 4);
    float* s1v     = (float*)alloc(NODES * 4);
    unsigned short* Abf = (unsigned short*)alloc((size_t)NODES * INF_ * 2);
    unsigned short* Zb  = (unsigned short*)alloc((size_t)NODES * HIDF * 2);
    unsigned short* H1b = (unsigned short*)alloc((size_t)NODES * HIDF * 2);

    // ---- prep: weights, folds, zero degrees, feat->bf16 (all graph-independent) ----
    prep0<<<PREP_BLKS, 512, 0, stream>>>(W1, W2, Wg, attn_l, attn_r, bg, W3, feat,
                                         W1t, W2t, WL, WR, WV, cdot, deg, Abf);
    deg_kernel<<<EDGE_BLKS, 256, 0, stream>>>(src, dst, deg_o, deg_i);
    scan_inv<<<1, SCAN_T, 0, stream>>>(deg_i, deg_o, rowptr, cursor, inv_o, inv_i);
    csr_fill<<<EDGE_BLKS, 256, 0, stream>>>(src, dst, cursor, csr_src);

    // ---- GraphConv 1: Zb = inv_o*(Abf@W1) ; gather -> H1b ----
    mfma_gemm<INF_><<<dim3((NODES + 63) / 64, 2), 256, 0, stream>>>(Abf, W1t, inv_o, Zb);
    gc_gather<1><<<NODES, 64, 0, stream>>>(rowptr, csr_src, Zb, inv_i, b1, H1b,
                                           nullptr, nullptr, nullptr, nullptr, nullptr,
                                           nullptr);

    // ---- GraphConv 2: Zb = inv_o*(H1b@W2) ; gather -> el/er/zeta ----
    mfma_gemm<HIDF><<<dim3((NODES + 63) / 64, 2), 256, 0, stream>>>(H1b, W2t, inv_o, Zb);
    gc_gather<2><<<NODES, 64, 0, stream>>>(rowptr, csr_src, Zb, inv_i, b2, nullptr,
                                           WL, WR, WV, el, er, zeta);

    // ---- GAT collapsed -> s1v ----
    gat_s1<<<NODES, 64, 0, stream>>>(rowptr, csr_src, (const float4*)el, (const float4*)er,
                                     (const float4*)zeta, inv_o, cdot, s1v);

    // ---- GC3 ----
    gc3_gather<<<NODES, 64, 0, stream>>>(rowptr, csr_src, s1v, inv_i, b3, (float*)d_out);
}